// Round 9
// baseline (1207.098 us; speedup 1.0000x reference)
//
#include <hip/hip_runtime.h>
#include <hip/hip_bf16.h>

typedef unsigned short u16;
typedef unsigned int   u32;

#define COUT 128
#define KNB  27

typedef __attribute__((ext_vector_type(8))) __bf16 bf16x8;
typedef __attribute__((ext_vector_type(4))) float  f32x4;

// Stats / BN params / dtype flags / bf16 weights in device globals.
// NOTE: device symbols must NEVER be passed as host-side kernel args
// (host shadow address != device address -> GPU fault). Select via template.
__device__ float g_sum[2][128], g_sq[2][128];
__device__ float g_colsum[64], g_G[4096];
__device__ float g_sc[3][128], g_sh[3][128];
__device__ int   g_f32;   // 1 if float input tensors are fp32, 0 if bf16
__device__ int   g_i64;   // 1 if nbr is int64 (read as int32 pairs)
__device__ u16   g_W1t[KNB * 128 * 64];   // [k][d][c] bf16
__device__ u16   g_W2t[KNB * 128 * 128];  // [k][d][c] bf16

__device__ __forceinline__ float b2f(u32 u) {
    union { float f; u32 i; } v; v.i = u << 16; return v.f;
}
__device__ __forceinline__ u16 f2b(float f) {
    union { float f; u32 i; } v; v.f = f;
    u32 r = v.i + 0x7fffu + ((v.i >> 16) & 1u);
    return (u16)(r >> 16);
}
__device__ __forceinline__ float ldf(const void* p, int i, bool f32) {
    return f32 ? ((const float*)p)[i] : b2f((u32)((const u16*)p)[i]);
}

__global__ void probe_zero_kernel(const u16* __restrict__ g1w, const int* __restrict__ nbr)
{
    int t = threadIdx.x;
    if (t == 0) {
        g_f32 = (g1w[0] == 0) ? 1 : 0;   // fp32 1.0f low word == 0
        g_i64 = ((nbr[1] | nbr[3] | nbr[5] | nbr[7]) == 0) ? 1 : 0;
    }
    for (int i = t; i < 128; i += 256) {
        g_sum[0][i] = 0.f; g_sq[0][i] = 0.f;
        g_sum[1][i] = 0.f; g_sq[1][i] = 0.f;
    }
    for (int i = t; i < 64; i += 256) g_colsum[i] = 0.f;
    for (int i = t; i < 4096; i += 256) g_G[i] = 0.f;
}

// Transpose+convert W1/W2 (fp32 or bf16 [k][c][d]) -> bf16 [k][d][c] globals
__global__ void convert_w_kernel(const void* __restrict__ W1, const void* __restrict__ W2)
{
    const bool f32 = (g_f32 != 0);
    const int total1 = KNB * 64 * 128;
    const int total2 = KNB * 128 * 128;
    for (int e = blockIdx.x * 256 + threadIdx.x; e < total1 + total2;
         e += gridDim.x * 256) {
        if (e < total1) {
            int k = e / (64 * 128), r = e % (64 * 128);
            int c = r / 128, d = r % 128;
            g_W1t[(k * 128 + d) * 64 + c] = f2b(ldf(W1, e, f32));
        } else {
            int e2 = e - total1;
            int k = e2 / (128 * 128), r = e2 % (128 * 128);
            int c = r / 128, d = r % 128;
            g_W2t[(k * 128 + d) * 128 + c] = f2b(ldf(W2, e2, f32));
        }
    }
}

// MFMA gather-conv, software-pipelined:
//   out[n,d] = sum_k sum_c src[nbr[n,k],c] * W[k,c,d]
// Block: 128 rows x 128 cols; 4 waves; wave w computes m-tiles 2w,2w+1.
// Pipeline: all 27 indices preloaded to LDS once; per (k,chunk) iteration the
// prefetched registers are written to LDS, then the NEXT iteration's global
// loads are ISSUED before the MFMA phase, so gather latency overlaps compute.
template<int CIN, int BN_SEL, bool SRC_F32, bool OUTF32, int WSEL>
__global__ __launch_bounds__(256, 2)
void spconv_mfma(const void* __restrict__ srcv, const int* __restrict__ nbr,
                 void* __restrict__ outv, int N)
{
    constexpr int NCHUNK = CIN / 64;
    constexpr int NITER  = KNB * NCHUNK;
    const u16* __restrict__ Wt = (WSEL == 1) ? g_W1t : g_W2t;
    __shared__ u16 As[8 * 2 * 512];    // 16KB: 8 mtiles x 2 ksteps x 1KB slabs
    __shared__ u16 Bs[8 * 2 * 512];    // 16KB
    __shared__ int sidx[KNB * 128];    // 13.5KB: [k][row]

    const bool i64 = (g_i64 != 0);
    const int t    = threadIdx.x;
    const int lane = t & 63;
    const int w    = t >> 6;           // wave id 0..3
    const int m    = t & 15;           // staging: row/d within tile
    const int q4   = (t >> 4) & 3;     // staging: 16B column sub-slice
    const int s_st = w >> 1;           // staging kstep handled by this wave
    const int par  = w & 1;            // staging tile parity
    const int n0   = blockIdx.x * 128;
    const int coff = (s_st * 4 + q4) * 8;   // channel offset within 64-chunk

    // ---- load ALL neighbor indices once
    for (int e = t; e < KNB * 128; e += 256) {
        int r = e >> 5;                 // 0..127 (e/32? no) -- careful: use div
        r = e / KNB; int k = e - r * KNB;
        int gr = n0 + r, ri = 0;
        if (gr < N) {
            size_t gi = (size_t)gr * KNB + k;
            ri = i64 ? nbr[2 * gi] : nbr[gi];
            if ((u32)ri >= (u32)N) ri = 0;
        }
        sidx[k * 128 + r] = ri;
    }

    // ---- hoist BN params (per-chunk) into registers
    float bn_sc[NCHUNK][8], bn_sh[NCHUNK][8];
    if (BN_SEL >= 0) {
#pragma unroll
        for (int ch = 0; ch < NCHUNK; ++ch)
#pragma unroll
            for (int j = 0; j < 8; ++j) {
                bn_sc[ch][j] = g_sc[BN_SEL][ch * 64 + coff + j];
                bn_sh[ch][j] = g_sh[BN_SEL][ch * 64 + coff + j];
            }
    }

    f32x4 acc[2][8];
#pragma unroll
    for (int a = 0; a < 2; ++a)
#pragma unroll
        for (int b = 0; b < 8; ++b) acc[a][b] = (f32x4){0.f, 0.f, 0.f, 0.f};

    uint4  pa16[4];
    float4 pa32[8];
    uint4  pb[4];

    __syncthreads();   // sidx visible

    // ---- issue prefetch for kc = 0
    {
        const int k2 = 0, c02 = 0;
#pragma unroll
        for (int i = 0; i < 4; ++i) {
            int tile = 2 * i + par;
            int row = sidx[k2 * 128 + tile * 16 + m];
            if (SRC_F32) {
                const float* p = (const float*)srcv + (size_t)row * CIN + c02 + coff;
                pa32[2 * i]     = *(const float4*)p;
                pa32[2 * i + 1] = *(const float4*)(p + 4);
            } else {
                const u16* p = (const u16*)srcv + (size_t)row * CIN + c02 + coff;
                pa16[i] = *(const uint4*)p;
            }
            const u16* pw = Wt + ((size_t)k2 * 128 + tile * 16 + m) * CIN + c02 + coff;
            pb[i] = *(const uint4*)pw;
        }
    }

    for (int kc = 0; kc < NITER; ++kc) {
        const int ch = (NCHUNK == 1) ? 0 : (kc & 1);
        __syncthreads();   // MFMA(kc-1) finished reading LDS
        // ---- write prefetched (kc) to LDS (implicit vmcnt wait here)
#pragma unroll
        for (int i = 0; i < 4; ++i) {
            int tile = 2 * i + par;
            float v[8];
            if (SRC_F32) {
                v[0]=pa32[2*i].x;   v[1]=pa32[2*i].y;   v[2]=pa32[2*i].z;   v[3]=pa32[2*i].w;
                v[4]=pa32[2*i+1].x; v[5]=pa32[2*i+1].y; v[6]=pa32[2*i+1].z; v[7]=pa32[2*i+1].w;
            } else {
                uint4 u = pa16[i];
                v[0]=b2f(u.x & 0xffffu); v[1]=b2f(u.x >> 16);
                v[2]=b2f(u.y & 0xffffu); v[3]=b2f(u.y >> 16);
                v[4]=b2f(u.z & 0xffffu); v[5]=b2f(u.z >> 16);
                v[6]=b2f(u.w & 0xffffu); v[7]=b2f(u.w >> 16);
            }
            if (BN_SEL >= 0) {
#pragma unroll
                for (int j = 0; j < 8; ++j)
                    v[j] = fmaxf(fmaf(v[j], bn_sc[ch][j], bn_sh[ch][j]), 0.f);
            }
            uint4 pk;
            pk.x = (u32)f2b(v[0]) | ((u32)f2b(v[1]) << 16);
            pk.y = (u32)f2b(v[2]) | ((u32)f2b(v[3]) << 16);
            pk.z = (u32)f2b(v[4]) | ((u32)f2b(v[5]) << 16);
            pk.w = (u32)f2b(v[6]) | ((u32)f2b(v[7]) << 16);
            *(uint4*)&As[(tile * 2 + s_st) * 512 + lane * 8] = pk;
            *(uint4*)&Bs[(tile * 2 + s_st) * 512 + lane * 8] = pb[i];
        }
        // ---- issue prefetch for kc+1 (overlaps barrier + MFMA below)
        if (kc + 1 < NITER) {
            const int kn  = kc + 1;
            const int k2  = (NCHUNK == 1) ? kn : (kn >> 1);
            const int c02 = (NCHUNK == 1) ? 0 : ((kn & 1) << 6);
#pragma unroll
            for (int i = 0; i < 4; ++i) {
                int tile = 2 * i + par;
                int row = sidx[k2 * 128 + tile * 16 + m];
                if (SRC_F32) {
                    const float* p = (const float*)srcv + (size_t)row * CIN + c02 + coff;
                    pa32[2 * i]     = *(const float4*)p;
                    pa32[2 * i + 1] = *(const float4*)(p + 4);
                } else {
                    const u16* p = (const u16*)srcv + (size_t)row * CIN + c02 + coff;
                    pa16[i] = *(const uint4*)p;
                }
                const u16* pw = Wt + ((size_t)k2 * 128 + tile * 16 + m) * CIN + c02 + coff;
                pb[i] = *(const uint4*)pw;
            }
        }
        __syncthreads();   // LDS writes visible
        // ---- MFMA: 2 ksteps x 2 mtiles x 8 ntiles
#pragma unroll
        for (int s = 0; s < 2; ++s) {
            bf16x8 afr[2];
#pragma unroll
            for (int mt = 0; mt < 2; ++mt)
                afr[mt] = *(const bf16x8*)&As[(((2 * w + mt) * 2 + s) * 512) + lane * 8];
#pragma unroll
            for (int nt = 0; nt < 8; ++nt) {
                bf16x8 bfr = *(const bf16x8*)&Bs[((nt * 2 + s) * 512) + lane * 8];
                acc[0][nt] = __builtin_amdgcn_mfma_f32_16x16x32_bf16(
                    afr[0], bfr, acc[0][nt], 0, 0, 0);
                acc[1][nt] = __builtin_amdgcn_mfma_f32_16x16x32_bf16(
                    afr[1], bfr, acc[1][nt], 0, 0, 0);
            }
        }
    }

    // ---- epilogue: C/D layout col=lane&15, row=(lane>>4)*4+reg
    const int q = lane >> 4, n = lane & 15;
#pragma unroll
    for (int mt = 0; mt < 2; ++mt) {
#pragma unroll
        for (int r4 = 0; r4 < 4; ++r4) {
            int gr = n0 + (2 * w + mt) * 16 + q * 4 + r4;
            if (gr < N) {
#pragma unroll
                for (int nt = 0; nt < 8; ++nt) {
                    float val = acc[mt][nt][r4];
                    size_t off = (size_t)gr * COUT + nt * 16 + n;
                    if (OUTF32) ((float*)outv)[off] = val;
                    else        ((u16*)outv)[off]  = f2b(val);
                }
            }
        }
    }
}

template<int SEL, bool F32>
__global__ __launch_bounds__(256)
void stats_kernel(const void* __restrict__ v, int N)
{
    const int t = threadIdx.x;
    const int c = t & 127;
    const int half = t >> 7;
    float s = 0.f, q = 0.f;
    for (int r = blockIdx.x * 2 + half; r < N; r += gridDim.x * 2) {
        size_t idx = (size_t)r * COUT + c;
        float x = F32 ? ((const float*)v)[idx] : b2f((u32)((const u16*)v)[idx]);
        s += x; q += x * x;
    }
    __shared__ float ss[256], qq[256];
    ss[t] = s; qq[t] = q;
    __syncthreads();
    if (t < 128) {
        atomicAdd(&g_sum[SEL][c], ss[t] + ss[t + 128]);
        atomicAdd(&g_sq[SEL][c],  qq[t] + qq[t + 128]);
    }
}

template<int SEL>
__global__ void finalize_kernel(const void* __restrict__ g, const void* __restrict__ b,
                                float invN)
{
    const bool f32 = (g_f32 != 0);
    int c = threadIdx.x;
    float mu  = g_sum[SEL][c] * invN;
    float var = fmaxf(g_sq[SEL][c] * invN - mu * mu, 0.f);
    float rs  = rsqrtf(var + 1e-5f);
    float sc  = rs * ldf(g, c, f32);
    g_sc[SEL][c] = sc;
    g_sh[SEL][c] = ldf(b, c, f32) - mu * sc;
}

// Gram stats of x: G = X^T X (64x64), colsum = sum_n x[n,:]
__global__ __launch_bounds__(256)
void xstats_kernel(const void* __restrict__ xv, int N)
{
    __shared__ float xs[16 * 64];
    const bool f32 = (g_f32 != 0);
    const int t  = threadIdx.x;
    const int c  = t >> 2;
    const int cb = (t & 3) * 16;
    float acc[16];
#pragma unroll
    for (int j = 0; j < 16; ++j) acc[j] = 0.f;
    float cs = 0.f;

    for (int r0 = blockIdx.x * 16; r0 < N; r0 += gridDim.x * 16) {
        __syncthreads();
        {
            int e = t * 4;
            int rr = e >> 6, qq = e & 63;
            int row = r0 + rr;
            size_t off = (size_t)min(row, N - 1) * 64 + qq;
            bool ok = (row < N);
            float v0, v1, v2, v3;
            if (f32) {
                float4 vv = *(const float4*)((const float*)xv + off);
                v0 = vv.x; v1 = vv.y; v2 = vv.z; v3 = vv.w;
            } else {
                uint2 u = *(const uint2*)((const u16*)xv + off);
                v0 = b2f(u.x & 0xffffu); v1 = b2f(u.x >> 16);
                v2 = b2f(u.y & 0xffffu); v3 = b2f(u.y >> 16);
            }
            xs[e + 0] = ok ? v0 : 0.f;
            xs[e + 1] = ok ? v1 : 0.f;
            xs[e + 2] = ok ? v2 : 0.f;
            xs[e + 3] = ok ? v3 : 0.f;
        }
        __syncthreads();
#pragma unroll
        for (int rr = 0; rr < 16; ++rr) {
            float a = xs[rr * 64 + c];
#pragma unroll
            for (int j = 0; j < 16; ++j)
                acc[j] = fmaf(a, xs[rr * 64 + cb + j], acc[j]);
        }
        if (t < 64) {
#pragma unroll
            for (int rr = 0; rr < 16; ++rr) cs += xs[rr * 64 + t];
        }
    }
#pragma unroll
    for (int j = 0; j < 16; ++j) atomicAdd(&g_G[c * 64 + cb + j], acc[j]);
    if (t < 64) atomicAdd(&g_colsum[t], cs);
}

__global__ __launch_bounds__(128)
void finalize_d_kernel(const void* __restrict__ Wd, const void* __restrict__ gd,
                       const void* __restrict__ bd, float invN)
{
    __shared__ float Gs[64 * 64];
    const bool f32 = (g_f32 != 0);
    const int t = threadIdx.x;
    for (int e = t; e < 4096; e += 128) Gs[e] = g_G[e];
    __syncthreads();
    float w[64];
#pragma unroll
    for (int c = 0; c < 64; ++c) w[c] = ldf(Wd, c * 128 + t, f32);
    float s = 0.f, q = 0.f;
    for (int c = 0; c < 64; ++c) {
        float inner = 0.f;
#pragma unroll 8
        for (int cc = 0; cc < 64; ++cc) inner = fmaf(Gs[c * 64 + cc], w[cc], inner);
        q = fmaf(w[c], inner, q);
        s = fmaf(g_colsum[c], w[c], s);
    }
    float mu  = s * invN;
    float var = fmaxf(q * invN - mu * mu, 0.f);
    float rs  = rsqrtf(var + 1e-5f);
    float sc  = rs * ldf(gd, t, f32);
    g_sc[2][t] = sc;
    g_sh[2][t] = ldf(bd, t, f32) - mu * sc;
}

// out = relu(bn2(out)) + bn_d(x @ Wd), fp32 in/out on d_out
__global__ __launch_bounds__(256)
void finish_dense_kernel(const void* __restrict__ xv, const void* __restrict__ Wdv,
                         float* __restrict__ out, int N)
{
    __shared__ float Xs[64 * 68];
    __shared__ float Ws[64 * COUT];
    const bool f32 = (g_f32 != 0);
    const int t  = threadIdx.x;
    const int tx = t & 31;
    const int ty = t >> 5;
    const int n0 = blockIdx.x * 64;
    const int valid = min(64, N - n0);

    for (int e = t; e < 64 * 16; e += 256) {
        int mm = e >> 4;
        int qq = (e & 15) << 2;
        size_t off = (size_t)min(n0 + mm, N - 1) * 64 + qq;
        float v0, v1, v2, v3;
        if (f32) {
            float4 vv = *(const float4*)((const float*)xv + off);
            v0 = vv.x; v1 = vv.y; v2 = vv.z; v3 = vv.w;
        } else {
            uint2 u = *(const uint2*)((const u16*)xv + off);
            v0 = b2f(u.x & 0xffffu); v1 = b2f(u.x >> 16);
            v2 = b2f(u.y & 0xffffu); v3 = b2f(u.y >> 16);
        }
        *(float4*)&Xs[mm * 68 + qq] = make_float4(v0, v1, v2, v3);
    }
    if (f32) {
        const float* Wp = (const float*)Wdv;
        for (int e = t; e < (64 * COUT) / 8; e += 256) {
            int l = e << 3;
            float4 a = *(const float4*)(Wp + l);
            float4 b = *(const float4*)(Wp + l + 4);
            float* dst = &Ws[l];
            dst[0]=a.x; dst[1]=a.y; dst[2]=a.z; dst[3]=a.w;
            dst[4]=b.x; dst[5]=b.y; dst[6]=b.z; dst[7]=b.w;
        }
    } else {
        const u16* Wp = (const u16*)Wdv;
        for (int e = t; e < (64 * COUT) / 8; e += 256) {
            int l = e << 3;
            uint4 u = *(const uint4*)(Wp + l);
            float* dst = &Ws[l];
            dst[0] = b2f(u.x & 0xffffu); dst[1] = b2f(u.x >> 16);
            dst[2] = b2f(u.y & 0xffffu); dst[3] = b2f(u.y >> 16);
            dst[4] = b2f(u.z & 0xffffu); dst[5] = b2f(u.z >> 16);
            dst[6] = b2f(u.w & 0xffffu); dst[7] = b2f(u.w >> 16);
        }
    }
    __syncthreads();

    float acc[8][4];
#pragma unroll
    for (int mm = 0; mm < 8; ++mm)
#pragma unroll
        for (int j = 0; j < 4; ++j) acc[mm][j] = 0.f;

#pragma unroll 2
    for (int c = 0; c < 64; ++c) {
        float4 wv = *(const float4*)&Ws[c * COUT + tx * 4];
#pragma unroll
        for (int mm = 0; mm < 8; ++mm) {
            float a = Xs[(ty * 8 + mm) * 68 + c];
            acc[mm][0] = fmaf(a, wv.x, acc[mm][0]);
            acc[mm][1] = fmaf(a, wv.y, acc[mm][1]);
            acc[mm][2] = fmaf(a, wv.z, acc[mm][2]);
            acc[mm][3] = fmaf(a, wv.w, acc[mm][3]);
        }
    }

    const int d = tx * 4;
    float s2r[4] = {g_sc[1][d], g_sc[1][d+1], g_sc[1][d+2], g_sc[1][d+3]};
    float h2r[4] = {g_sh[1][d], g_sh[1][d+1], g_sh[1][d+2], g_sh[1][d+3]};
    float sdr[4] = {g_sc[2][d], g_sc[2][d+1], g_sc[2][d+2], g_sc[2][d+3]};
    float hdr[4] = {g_sh[2][d], g_sh[2][d+1], g_sh[2][d+2], g_sh[2][d+3]};
#pragma unroll
    for (int mm = 0; mm < 8; ++mm) {
        int rr = ty * 8 + mm;
        if (rr < valid) {
            float* p = out + (size_t)(n0 + rr) * COUT + d;
            float4 raw = *(float4*)p;
            float o0 = fmaxf(fmaf(raw.x, s2r[0], h2r[0]), 0.f) + fmaf(acc[mm][0], sdr[0], hdr[0]);
            float o1 = fmaxf(fmaf(raw.y, s2r[1], h2r[1]), 0.f) + fmaf(acc[mm][1], sdr[1], hdr[1]);
            float o2 = fmaxf(fmaf(raw.z, s2r[2], h2r[2]), 0.f) + fmaf(acc[mm][2], sdr[2], hdr[2]);
            float o3 = fmaxf(fmaf(raw.w, s2r[3], h2r[3]), 0.f) + fmaf(acc[mm][3], sdr[3], hdr[3]);
            *(float4*)p = make_float4(o0, o1, o2, o3);
        }
    }
}

extern "C" void kernel_launch(void* const* d_in, const int* in_sizes, int n_in,
                              void* d_out, int out_size, void* d_ws, size_t ws_size,
                              hipStream_t stream)
{
    const void* x   = d_in[0];
    const int*  nbr = (const int*)d_in[1];
    const void* W1  = d_in[2];
    const void* g1  = d_in[3];
    const void* b1  = d_in[4];
    const void* W2  = d_in[5];
    const void* g2  = d_in[6];
    const void* b2  = d_in[7];
    const void* Wd  = d_in[8];
    const void* gd  = d_in[9];
    const void* bd  = d_in[10];
    float* out = (float*)d_out;

    const int N = in_sizes[0] / 64;
    u16* tmp = (u16*)d_ws;                 // [N,128] bf16 conv1 raw — only ws use

    const int nbm = (N + 127) / 128;       // MFMA conv blocks
    const int nbf = (N + 63) / 64;         // finish blocks
    const float invN = 1.f / (float)N;

    hipLaunchKernelGGL(probe_zero_kernel, dim3(1), dim3(256), 0, stream,
                       (const u16*)g1, nbr);
    hipLaunchKernelGGL(convert_w_kernel, dim3(1024), dim3(256), 0, stream, W1, W2);
    // conv1 raw -> tmp (bf16), MFMA
    hipLaunchKernelGGL((spconv_mfma<64, -1, true, false, 1>), dim3(nbm), dim3(256), 0, stream,
                       x, nbr, tmp, N);
    hipLaunchKernelGGL((stats_kernel<0, false>), dim3(512), dim3(256), 0, stream, tmp, N);
    hipLaunchKernelGGL((finalize_kernel<0>), dim3(1), dim3(128), 0, stream, g1, b1, invN);
    // conv2 (bn1+relu fused into A-staging) -> d_out raw (fp32), MFMA
    hipLaunchKernelGGL((spconv_mfma<128, 0, false, true, 2>), dim3(nbm), dim3(256), 0, stream,
                       tmp, nbr, out, N);
    hipLaunchKernelGGL((stats_kernel<1, true>), dim3(512), dim3(256), 0, stream, out, N);
    hipLaunchKernelGGL((finalize_kernel<1>), dim3(1), dim3(128), 0, stream, g2, b2, invN);
    // dense-branch stats without materializing x@Wd
    hipLaunchKernelGGL(xstats_kernel, dim3(256), dim3(256), 0, stream, x, N);
    hipLaunchKernelGGL(finalize_d_kernel, dim3(1), dim3(128), 0, stream, Wd, gd, bd, invN);
    // out = relu(bn2(out)) + bn_d(x@Wd)
    hipLaunchKernelGGL(finish_dense_kernel, dim3(nbf), dim3(256), 0, stream,
                       x, Wd, out, N);
}